// Round 1
// baseline (759.226 us; speedup 1.0000x reference)
//
#include <hip/hip_runtime.h>
#include <math.h>

#define NN 20000
#define NE 320000
#define DIM 256

typedef __bf16 bf16x8 __attribute__((ext_vector_type(8)));
typedef float f32x4 __attribute__((ext_vector_type(4)));
typedef int i32x4 __attribute__((ext_vector_type(4)));
typedef unsigned short u16x4 __attribute__((ext_vector_type(4)));

union B8 { i32x4 i; bf16x8 b; };

__device__ __forceinline__ unsigned short f2bf(float f) {
  unsigned int u; __builtin_memcpy(&u, &f, 4);
  u += 0x7fffu + ((u >> 16) & 1u);
  return (unsigned short)(u >> 16);
}
__device__ __forceinline__ float bf2f(unsigned short h) {
  unsigned int u = ((unsigned int)h) << 16;
  float f; __builtin_memcpy(&f, &u, 4);
  return f;
}

// Pack one f32 [256][256] weight (row-major W[j_out][k]) into MFMA B-fragment order, bf16.
// Index t = ks*1024 + ct*64 + lane ; each thread packs 8 contiguous k for (col,k0).
__global__ __launch_bounds__(256) void pack_w(const float* __restrict__ W,
                                              unsigned short* __restrict__ wf) {
  int t = blockIdx.x * 256 + threadIdx.x;    // 0..8191
  int lane = t & 63, ct = (t >> 6) & 15, ks = t >> 10;
  int col = ct * 16 + (lane & 15);
  int k0 = ks * 32 + (lane >> 4) * 8;
  const float* src = W + col * 256 + k0;
  unsigned int h[8];
#pragma unroll
  for (int j = 0; j < 8; j++) h[j] = f2bf(src[j]);
  i32x4 v;
  v.x = (int)(h[0] | (h[1] << 16));
  v.y = (int)(h[2] | (h[3] << 16));
  v.z = (int)(h[4] | (h[5] << 16));
  v.w = (int)(h[6] | (h[7] << 16));
  ((i32x4*)wf)[t] = v;
}

// Shared 64x256 bf16 A-tile (XOR-swizzled) x packed weight -> acc[4][4] f32x4 per wave.
__device__ __forceinline__ void gemm_tile(const unsigned short* zs,
                                          const unsigned short* wf,
                                          int lane, int wv, f32x4 (&acc)[4][4]) {
#pragma unroll 1
  for (int ksI = 0; ksI < 8; ksI++) {
    bf16x8 afr[4], bfr[4];
#pragma unroll
    for (int rt = 0; rt < 4; rt++) {
      int row = rt * 16 + (lane & 15);
      int k = ksI * 32 + (lane >> 4) * 8;
      int byteo = (row * 512 + k * 2) ^ ((row & 7) << 4);
      B8 u; u.i = *(const i32x4*)((const char*)zs + byteo);
      afr[rt] = u.b;
    }
#pragma unroll
    for (int ct = 0; ct < 4; ct++) {
      B8 u; u.i = ((const i32x4*)wf)[ksI * 1024 + (wv * 4 + ct) * 64 + lane];
      bfr[ct] = u.b;
    }
#pragma unroll
    for (int rt = 0; rt < 4; rt++)
#pragma unroll
      for (int ct = 0; ct < 4; ct++)
        acc[rt][ct] = __builtin_amdgcn_mfma_f32_16x16x32_bf16(afr[rt], bfr[ct], acc[rt][ct], 0, 0, 0);
  }
}

// q = x @ Wq^T  (64-row tiles, tail-masked)
__global__ __launch_bounds__(256) void q_kernel(const float* __restrict__ x,
                                                const unsigned short* __restrict__ wf,
                                                float* __restrict__ q) {
  __shared__ unsigned short zs[64 * 256];
  int tid = threadIdx.x, lane = tid & 63, wv = tid >> 6;
  int r0 = blockIdx.x * 64;
  int dcol = lane * 4;
#pragma unroll 4
  for (int rr = 0; rr < 16; rr++) {
    int r = rr * 4 + wv;
    int row = r0 + r;
    f32x4 a = {0.f, 0.f, 0.f, 0.f};
    if (row < NN) a = *(const f32x4*)(x + (size_t)row * DIM + dcol);
    u16x4 z;
    z.x = f2bf(a.x); z.y = f2bf(a.y); z.z = f2bf(a.z); z.w = f2bf(a.w);
    int byteo = (r * 512 + dcol * 2) ^ ((r & 7) << 4);
    *(u16x4*)((char*)zs + byteo) = z;
  }
  __syncthreads();
  f32x4 acc[4][4];
#pragma unroll
  for (int rt = 0; rt < 4; rt++)
#pragma unroll
    for (int ct = 0; ct < 4; ct++) acc[rt][ct] = (f32x4){0.f, 0.f, 0.f, 0.f};
  gemm_tile(zs, wf, lane, wv, acc);
  int cq = lane & 15, rq = lane >> 4;
#pragma unroll
  for (int ct = 0; ct < 4; ct++) {
    int col = wv * 64 + ct * 16 + cq;
#pragma unroll
    for (int rt = 0; rt < 4; rt++) {
#pragma unroll
      for (int j = 0; j < 4; j++) {
        int row = r0 + rt * 16 + rq * 4 + j;
        if (row < NN) q[(size_t)row * DIM + col] = acc[rt][ct][j];
      }
    }
  }
}

// Per 64-edge tile: Z = ea * x[dst]; v = Z@Wv^T (bf16->ws); edge_out = Z@We^T + be (f32->d_out);
// k = Z@Wk^T staged to LDS; scores[e][h] = dot(q[src], k)/sqrt(32) -> ws.
__global__ __launch_bounds__(256) void edge_kernel(
    const float* __restrict__ x, const int* __restrict__ ei,
    const float* __restrict__ ea,
    const unsigned short* __restrict__ wfk, const unsigned short* __restrict__ wfv,
    const unsigned short* __restrict__ wfe, const float* __restrict__ be,
    const float* __restrict__ q, unsigned short* __restrict__ vws,
    float* __restrict__ scores, float* __restrict__ edge_out) {
  __shared__ unsigned short zs[64 * 256];
  __shared__ int dsts[64], srcs[64];
  int tid = threadIdx.x, lane = tid & 63, wv = tid >> 6;
  int e0 = blockIdx.x * 64;
  if (tid < 64) {
    srcs[tid] = ei[e0 + tid];
    dsts[tid] = ei[NE + e0 + tid];
  }
  __syncthreads();
  // phase 1: Z tile (bf16, swizzled)
  int dcol = lane * 4;
#pragma unroll 4
  for (int rr = 0; rr < 16; rr++) {
    int r = rr * 4 + wv;
    f32x4 a = *(const f32x4*)(ea + (size_t)(e0 + r) * DIM + dcol);
    f32x4 b = *(const f32x4*)(x + (size_t)dsts[r] * DIM + dcol);
    u16x4 z;
    z.x = f2bf(a.x * b.x); z.y = f2bf(a.y * b.y);
    z.z = f2bf(a.z * b.z); z.w = f2bf(a.w * b.w);
    int byteo = (r * 512 + dcol * 2) ^ ((r & 7) << 4);
    *(u16x4*)((char*)zs + byteo) = z;
  }
  __syncthreads();
  int cq = lane & 15, rq = lane >> 4;
#pragma unroll 1
  for (int w3 = 0; w3 < 3; w3++) {
    const unsigned short* wf = (w3 == 0) ? wfv : (w3 == 1) ? wfe : wfk;
    f32x4 acc[4][4];
#pragma unroll
    for (int rt = 0; rt < 4; rt++)
#pragma unroll
      for (int ct = 0; ct < 4; ct++) acc[rt][ct] = (f32x4){0.f, 0.f, 0.f, 0.f};
    gemm_tile(zs, wf, lane, wv, acc);
    if (w3 == 0) {
#pragma unroll
      for (int ct = 0; ct < 4; ct++) {
        int col = wv * 64 + ct * 16 + cq;
#pragma unroll
        for (int rt = 0; rt < 4; rt++)
#pragma unroll
          for (int j = 0; j < 4; j++) {
            int row = rt * 16 + rq * 4 + j;
            vws[(size_t)(e0 + row) * DIM + col] = f2bf(acc[rt][ct][j]);
          }
      }
    } else if (w3 == 1) {
#pragma unroll
      for (int ct = 0; ct < 4; ct++) {
        int col = wv * 64 + ct * 16 + cq;
        float bias = be[col];
#pragma unroll
        for (int rt = 0; rt < 4; rt++)
#pragma unroll
          for (int j = 0; j < 4; j++) {
            int row = rt * 16 + rq * 4 + j;
            edge_out[(size_t)(e0 + row) * DIM + col] = acc[rt][ct][j] + bias;
          }
      }
    } else {
      __syncthreads();  // all waves done reading Z from zs
#pragma unroll
      for (int ct = 0; ct < 4; ct++) {
        int col = wv * 64 + ct * 16 + cq;
#pragma unroll
        for (int rt = 0; rt < 4; rt++)
#pragma unroll
          for (int j = 0; j < 4; j++) {
            int row = rt * 16 + rq * 4 + j;
            zs[row * 256 + col] = f2bf(acc[rt][ct][j]);  // k tile, plain layout
          }
      }
      __syncthreads();
      // scores: 512 (edge,head) pairs, 2 per thread
#pragma unroll
      for (int s2 = 0; s2 < 2; s2++) {
        int sidx = s2 * 256 + tid;
        int r = sidx >> 3, h = sidx & 7;
        const unsigned short* kp = zs + r * 256 + h * 32;
        const float* qp = q + (size_t)srcs[r] * DIM + h * 32;
        float acs = 0.f;
#pragma unroll
        for (int c8 = 0; c8 < 4; c8++) {
          i32x4 kv = *(const i32x4*)(kp + c8 * 8);
          f32x4 qa = *(const f32x4*)(qp + c8 * 8);
          f32x4 qb = *(const f32x4*)(qp + c8 * 8 + 4);
          acs += bf2f((unsigned short)(kv.x & 0xffff)) * qa.x
               + bf2f((unsigned short)(kv.x >> 16)) * qa.y
               + bf2f((unsigned short)(kv.y & 0xffff)) * qa.z
               + bf2f((unsigned short)(kv.y >> 16)) * qa.w
               + bf2f((unsigned short)(kv.z & 0xffff)) * qb.x
               + bf2f((unsigned short)(kv.z >> 16)) * qb.y
               + bf2f((unsigned short)(kv.w & 0xffff)) * qb.z
               + bf2f((unsigned short)(kv.w >> 16)) * qb.w;
        }
        scores[(size_t)(e0 + r) * 8 + h] = acs * 0.17677669529663687f; // 1/sqrt(32)
      }
    }
  }
}

__global__ __launch_bounds__(256) void count_kernel(const int* __restrict__ ei,
                                                    int* __restrict__ counts) {
  int e = blockIdx.x * 256 + threadIdx.x;
  if (e < NE) atomicAdd(&counts[ei[e]], 1);
}

__global__ __launch_bounds__(256) void scan_kernel(const int* __restrict__ counts,
                                                   int* __restrict__ offs,
                                                   int* __restrict__ cursor) {
  __shared__ int tmp[256];
  __shared__ int carry;
  int tid = threadIdx.x;
  if (tid == 0) carry = 0;
  __syncthreads();
  for (int base = 0; base < NN; base += 256) {
    int i = base + tid;
    int v = (i < NN) ? counts[i] : 0;
    tmp[tid] = v;
    __syncthreads();
    for (int off = 1; off < 256; off <<= 1) {
      int t = (tid >= off) ? tmp[tid - off] : 0;
      __syncthreads();
      tmp[tid] += t;
      __syncthreads();
    }
    int incl = tmp[tid];
    int c0 = carry;
    if (i < NN) {
      offs[i] = c0 + incl - v;
      cursor[i] = c0 + incl - v;
    }
    __syncthreads();
    if (tid == 255) carry = c0 + incl;
    __syncthreads();
  }
  if (tid == 0) offs[NN] = carry;
}

__global__ __launch_bounds__(256) void fill_kernel(const int* __restrict__ ei,
                                                   int* __restrict__ cursor,
                                                   int* __restrict__ eids) {
  int e = blockIdx.x * 256 + threadIdx.x;
  if (e < NE) {
    int pos = atomicAdd(&cursor[ei[e]], 1);
    eids[pos] = e;
  }
}

// One wave per src node: online softmax over its edges + weighted v accumulation.
__global__ __launch_bounds__(256) void node_kernel(const int* __restrict__ offs,
                                                   const int* __restrict__ eids,
                                                   const float* __restrict__ scores,
                                                   const unsigned short* __restrict__ vws,
                                                   float* __restrict__ out) {
  int tid = threadIdx.x;
  int n = blockIdx.x * 4 + (tid >> 6);
  int lane = tid & 63, h = lane >> 3;
  int o0 = offs[n], deg = offs[n + 1] - o0;
  float m = -INFINITY, s = 0.f;
  float a0 = 0.f, a1 = 0.f, a2 = 0.f, a3 = 0.f;
  for (int i = 0; i < deg; i++) {
    int e = eids[o0 + i];
    float sc = scores[(size_t)e * 8 + h];
    float mn = fmaxf(m, sc);
    float scale = __expf(m - mn);
    float p = __expf(sc - mn);
    s = s * scale + p;
    m = mn;
    u16x4 v = *(const u16x4*)(vws + (size_t)e * DIM + lane * 4);
    a0 = a0 * scale + p * bf2f(v.x);
    a1 = a1 * scale + p * bf2f(v.y);
    a2 = a2 * scale + p * bf2f(v.z);
    a3 = a3 * scale + p * bf2f(v.w);
  }
  float inv = 1.f / (s + 1e-16f);
  f32x4 o;
  o.x = a0 * inv; o.y = a1 * inv; o.z = a2 * inv; o.w = a3 * inv;
  *(f32x4*)(out + (size_t)n * DIM + lane * 4) = o;
}

extern "C" void kernel_launch(void* const* d_in, const int* in_sizes, int n_in,
                              void* d_out, int out_size, void* d_ws, size_t ws_size,
                              hipStream_t stream) {
  const float* x = (const float*)d_in[0];
  const int* ei = (const int*)d_in[1];
  const float* ea = (const float*)d_in[2];
  const float* Wq = (const float*)d_in[3];
  const float* Wk = (const float*)d_in[4];
  const float* Wv = (const float*)d_in[5];
  const float* We = (const float*)d_in[6];
  const float* be = (const float*)d_in[7];

  float* out = (float*)d_out;                       // [NN, 256]
  float* edge_out = out + (size_t)NN * DIM;         // [NE, 256]
  float* q = out;                                   // reuse out region as q scratch
                                                    // (overwritten last by node_kernel)
  char* ws = (char*)d_ws;
  unsigned short* wfq = (unsigned short*)(ws + 0);
  unsigned short* wfk = (unsigned short*)(ws + 131072);
  unsigned short* wfv = (unsigned short*)(ws + 262144);
  unsigned short* wfe = (unsigned short*)(ws + 393216);
  unsigned short* vws = (unsigned short*)(ws + 524288);            // [NE,256] bf16
  float* scores = (float*)(ws + 524288 + 163840000);               // [NE,8] f32
  int* counts = (int*)(ws + 524288 + 163840000 + 10240000);
  int* offs = (int*)(ws + 524288 + 163840000 + 10240000 + 80000);
  int* cursor = (int*)(ws + 524288 + 163840000 + 10240000 + 160016);
  int* eids = (int*)(ws + 524288 + 163840000 + 10240000 + 240016);

  hipMemsetAsync(counts, 0, NN * sizeof(int), stream);

  pack_w<<<32, 256, 0, stream>>>(Wq, wfq);
  pack_w<<<32, 256, 0, stream>>>(Wk, wfk);
  pack_w<<<32, 256, 0, stream>>>(Wv, wfv);
  pack_w<<<32, 256, 0, stream>>>(We, wfe);

  q_kernel<<<(NN + 63) / 64, 256, 0, stream>>>(x, wfq, q);
  edge_kernel<<<NE / 64, 256, 0, stream>>>(x, ei, ea, wfk, wfv, wfe, be, q,
                                           vws, scores, edge_out);

  count_kernel<<<(NE + 255) / 256, 256, 0, stream>>>(ei, counts);
  scan_kernel<<<1, 256, 0, stream>>>(counts, offs, cursor);
  fill_kernel<<<(NE + 255) / 256, 256, 0, stream>>>(ei, cursor, eids);

  node_kernel<<<NN / 4, 256, 0, stream>>>(offs, eids, scores, vws, out);
}

// Round 2
// 613.597 us; speedup vs baseline: 1.2373x; 1.2373x over previous
//
#include <hip/hip_runtime.h>
#include <math.h>

#define NN 20000
#define NE 320000
#define DIM 256

typedef __bf16 bf16x8 __attribute__((ext_vector_type(8)));
typedef float f32x4 __attribute__((ext_vector_type(4)));
typedef int i32x4 __attribute__((ext_vector_type(4)));
typedef unsigned short u16x4 __attribute__((ext_vector_type(4)));

union B8 { i32x4 i; bf16x8 b; };

__device__ __forceinline__ unsigned short f2bf(float f) {
  unsigned int u; __builtin_memcpy(&u, &f, 4);
  u += 0x7fffu + ((u >> 16) & 1u);
  return (unsigned short)(u >> 16);
}
__device__ __forceinline__ float bf2f(unsigned short h) {
  unsigned int u = ((unsigned int)h) << 16;
  float f; __builtin_memcpy(&f, &u, 4);
  return f;
}

// Pack one f32 [256][256] weight (row-major W[j_out][k]) into MFMA fragment order, bf16.
// Index t = ks*1024 + ct*64 + lane ; each thread packs 8 contiguous k for (col,k0).
__global__ __launch_bounds__(256) void pack_w(const float* __restrict__ W,
                                              unsigned short* __restrict__ wf) {
  int t = blockIdx.x * 256 + threadIdx.x;    // 0..8191
  int lane = t & 63, ct = (t >> 6) & 15, ks = t >> 10;
  int col = ct * 16 + (lane & 15);
  int k0 = ks * 32 + (lane >> 4) * 8;
  const float* src = W + col * 256 + k0;
  unsigned int h[8];
#pragma unroll
  for (int j = 0; j < 8; j++) h[j] = f2bf(src[j]);
  i32x4 v;
  v.x = (int)(h[0] | (h[1] << 16));
  v.y = (int)(h[2] | (h[3] << 16));
  v.z = (int)(h[4] | (h[5] << 16));
  v.w = (int)(h[6] | (h[7] << 16));
  ((i32x4*)wf)[t] = v;
}

// ---------- q kernel (unchanged structure, 64-row tiles) ----------
__device__ __forceinline__ void gemm_tile(const unsigned short* zs,
                                          const unsigned short* wf,
                                          int lane, int wv, f32x4 (&acc)[4][4]) {
#pragma unroll 1
  for (int ksI = 0; ksI < 8; ksI++) {
    bf16x8 afr[4], bfr[4];
#pragma unroll
    for (int rt = 0; rt < 4; rt++) {
      int row = rt * 16 + (lane & 15);
      int k = ksI * 32 + (lane >> 4) * 8;
      int byteo = (row * 512 + k * 2) ^ ((row & 7) << 4);
      B8 u; u.i = *(const i32x4*)((const char*)zs + byteo);
      afr[rt] = u.b;
    }
#pragma unroll
    for (int ct = 0; ct < 4; ct++) {
      B8 u; u.i = ((const i32x4*)wf)[ksI * 1024 + (wv * 4 + ct) * 64 + lane];
      bfr[ct] = u.b;
    }
#pragma unroll
    for (int rt = 0; rt < 4; rt++)
#pragma unroll
      for (int ct = 0; ct < 4; ct++)
        acc[rt][ct] = __builtin_amdgcn_mfma_f32_16x16x32_bf16(afr[rt], bfr[ct], acc[rt][ct], 0, 0, 0);
  }
}

__global__ __launch_bounds__(256) void q_kernel(const float* __restrict__ x,
                                                const unsigned short* __restrict__ wf,
                                                float* __restrict__ q) {
  __shared__ unsigned short zs[64 * 256];
  int tid = threadIdx.x, lane = tid & 63, wv = tid >> 6;
  int r0 = blockIdx.x * 64;
  int dcol = lane * 4;
#pragma unroll 4
  for (int rr = 0; rr < 16; rr++) {
    int r = rr * 4 + wv;
    int row = r0 + r;
    f32x4 a = {0.f, 0.f, 0.f, 0.f};
    if (row < NN) a = *(const f32x4*)(x + (size_t)row * DIM + dcol);
    u16x4 z;
    z.x = f2bf(a.x); z.y = f2bf(a.y); z.z = f2bf(a.z); z.w = f2bf(a.w);
    int byteo = (r * 512 + dcol * 2) ^ ((r & 7) << 4);
    *(u16x4*)((char*)zs + byteo) = z;
  }
  __syncthreads();
  f32x4 acc[4][4];
#pragma unroll
  for (int rt = 0; rt < 4; rt++)
#pragma unroll
    for (int ct = 0; ct < 4; ct++) acc[rt][ct] = (f32x4){0.f, 0.f, 0.f, 0.f};
  gemm_tile(zs, wf, lane, wv, acc);
  int cq = lane & 15, rq = lane >> 4;
#pragma unroll
  for (int ct = 0; ct < 4; ct++) {
    int col = wv * 64 + ct * 16 + cq;
#pragma unroll
    for (int rt = 0; rt < 4; rt++) {
#pragma unroll
      for (int j = 0; j < 4; j++) {
        int row = r0 + rt * 16 + rq * 4 + j;
        if (row < NN) q[(size_t)row * DIM + col] = acc[rt][ct][j];
      }
    }
  }
}

// ---------- edge kernel v2: BM=128, 8 waves, swapped-operand MFMA, ----------
// ---------- register-ring prefetch, no k LDS round trip             ----------
__global__ __launch_bounds__(512) void edge_kernel(
    const float* __restrict__ x, const int* __restrict__ ei,
    const float* __restrict__ ea,
    const unsigned short* __restrict__ wfk, const unsigned short* __restrict__ wfv,
    const unsigned short* __restrict__ wfe, const float* __restrict__ be,
    const float* __restrict__ q, unsigned short* __restrict__ vws,
    float* __restrict__ scores, float* __restrict__ edge_out) {
  __shared__ unsigned short zs[128 * 256];   // 64 KiB, XOR-swizzled
  int tid = threadIdx.x, lane = tid & 63, wv = tid >> 6;
  int wm = wv >> 2, wn = wv & 3;             // 2 (row-half) x 4 (col-quad) waves
  int rq = lane >> 4, cl = lane & 15;
  int e0 = blockIdx.x * 128;

  // ---- stage Z = ea * x[dst], bf16, swizzled; rows wave-uniform -> coalesced ----
#pragma unroll
  for (int i = 0; i < 16; i++) {
    int r = i * 8 + wv;
    int dst = ei[NE + e0 + r];
    f32x4 a = *(const f32x4*)(ea + (size_t)(e0 + r) * DIM + lane * 4);
    f32x4 b = *(const f32x4*)(x + (size_t)dst * DIM + lane * 4);
    u16x4 z;
    z.x = f2bf(a.x * b.x); z.y = f2bf(a.y * b.y);
    z.z = f2bf(a.z * b.z); z.w = f2bf(a.w * b.w);
    int byteo = (r * 512 + lane * 8) ^ ((r & 7) << 4);
    *(u16x4*)((char*)zs + byteo) = z;
  }
  __syncthreads();

  const unsigned short* wfs[3] = {wfv, wfe, wfk};
  i32x4 wbuf[4][4];   // 4-slot ring, lead-2 weight-fragment prefetch (L2)
  i32x4 zbuf[2][4];   // 2-slot ring, lead-1 Z-fragment prefetch (LDS)
  f32x4 acc[4][4];

#define LOADW(S, SLOT)                                                         \
  {                                                                            \
    const unsigned short* wfp = wfs[(S) >> 3];                                 \
    _Pragma("unroll") for (int a = 0; a < 4; a++)                              \
        wbuf[SLOT][a] =                                                        \
            ((const i32x4*)wfp)[((S) & 7) * 1024 + (wn * 4 + a) * 64 + lane];  \
  }
#define LOADZ(S, SLOT)                                                         \
  {                                                                            \
    _Pragma("unroll") for (int b = 0; b < 4; b++) {                            \
      int row = wm * 64 + b * 16 + cl;                                         \
      int kk = ((S) & 7) * 32 + rq * 8;                                        \
      int byteo = (row * 512 + kk * 2) ^ ((row & 7) << 4);                     \
      zbuf[SLOT][b] = *(const i32x4*)((const char*)zs + byteo);                \
    }                                                                          \
  }
#define GEMM_PASS(P)                                                           \
  _Pragma("unroll") for (int a = 0; a < 4; a++)                                \
      _Pragma("unroll") for (int b = 0; b < 4; b++)                            \
          acc[a][b] = (f32x4){0.f, 0.f, 0.f, 0.f};                             \
  _Pragma("unroll") for (int ks = 0; ks < 8; ks++) {                           \
    const int step = (P) * 8 + ks;                                             \
    if (step + 2 < 24) LOADW(step + 2, (step + 2) & 3);                        \
    if (step + 1 < 24) LOADZ(step + 1, (step + 1) & 1);                        \
    _Pragma("unroll") for (int a = 0; a < 4; a++) {                            \
      B8 w; w.i = wbuf[step & 3][a];                                           \
      _Pragma("unroll") for (int b = 0; b < 4; b++) {                          \
        B8 z; z.i = zbuf[step & 1][b];                                         \
        acc[a][b] = __builtin_amdgcn_mfma_f32_16x16x32_bf16(w.b, z.b,          \
                                                            acc[a][b], 0, 0, 0); \
      }                                                                        \
    }                                                                          \
  }

  LOADW(0, 0); LOADW(1, 1);
  LOADZ(0, 0); LOADZ(1, 1);

  // ---- pass 0: v = Z @ Wv^T  (D[ch][edge] -> u16x4 per 4 contiguous ch) ----
  GEMM_PASS(0)
#pragma unroll
  for (int a = 0; a < 4; a++) {
    int ch = wn * 64 + a * 16 + rq * 4;
#pragma unroll
    for (int b = 0; b < 4; b++) {
      int edge = wm * 64 + b * 16 + cl;
      u16x4 o;
      o.x = f2bf(acc[a][b][0]); o.y = f2bf(acc[a][b][1]);
      o.z = f2bf(acc[a][b][2]); o.w = f2bf(acc[a][b][3]);
      *(u16x4*)(vws + (size_t)(e0 + edge) * DIM + ch) = o;
    }
  }

  // ---- pass 1: edge_out = Z @ We^T + be ----
  GEMM_PASS(1)
#pragma unroll
  for (int a = 0; a < 4; a++) {
    int ch = wn * 64 + a * 16 + rq * 4;
    f32x4 bias = *(const f32x4*)(be + ch);
#pragma unroll
    for (int b = 0; b < 4; b++) {
      int edge = wm * 64 + b * 16 + cl;
      f32x4 o = acc[a][b] + bias;
      *(f32x4*)(edge_out + (size_t)(e0 + edge) * DIM + ch) = o;
    }
  }

  // ---- pass 2: k = Z @ Wk^T, scores computed in-register ----
  GEMM_PASS(2)
#pragma unroll
  for (int b = 0; b < 4; b++) {
    int edge = wm * 64 + b * 16 + cl;
    int sr = ei[e0 + edge];
    const float* qp = q + (size_t)sr * DIM + wn * 64 + rq * 4;
    f32x4 q0 = *(const f32x4*)(qp);
    f32x4 q1 = *(const f32x4*)(qp + 16);
    f32x4 q2 = *(const f32x4*)(qp + 32);
    f32x4 q3 = *(const f32x4*)(qp + 48);
    float s0 = acc[0][b][0] * q0[0] + acc[0][b][1] * q0[1] +
               acc[0][b][2] * q0[2] + acc[0][b][3] * q0[3] +
               acc[1][b][0] * q1[0] + acc[1][b][1] * q1[1] +
               acc[1][b][2] * q1[2] + acc[1][b][3] * q1[3];
    float s1 = acc[2][b][0] * q2[0] + acc[2][b][1] * q2[1] +
               acc[2][b][2] * q2[2] + acc[2][b][3] * q2[3] +
               acc[3][b][0] * q3[0] + acc[3][b][1] * q3[1] +
               acc[3][b][2] * q3[2] + acc[3][b][3] * q3[3];
    s0 += __shfl_xor(s0, 16); s0 += __shfl_xor(s0, 32);
    s1 += __shfl_xor(s1, 16); s1 += __shfl_xor(s1, 32);
    if (lane < 16) {
      scores[(size_t)(e0 + edge) * 8 + wn * 2 + 0] = s0 * 0.17677669529663687f;
      scores[(size_t)(e0 + edge) * 8 + wn * 2 + 1] = s1 * 0.17677669529663687f;
    }
  }
#undef LOADW
#undef LOADZ
#undef GEMM_PASS
}

// ---------- CSR build ----------
__global__ __launch_bounds__(256) void count_kernel(const int* __restrict__ ei,
                                                    int* __restrict__ counts) {
  int e = blockIdx.x * 256 + threadIdx.x;
  if (e < NE) atomicAdd(&counts[ei[e]], 1);
}

__global__ __launch_bounds__(256) void scan_kernel(const int* __restrict__ counts,
                                                   int* __restrict__ offs,
                                                   int* __restrict__ cursor) {
  __shared__ int tmp[256];
  __shared__ int carry;
  int tid = threadIdx.x;
  if (tid == 0) carry = 0;
  __syncthreads();
  for (int base = 0; base < NN; base += 256) {
    int i = base + tid;
    int v = (i < NN) ? counts[i] : 0;
    tmp[tid] = v;
    __syncthreads();
    for (int off = 1; off < 256; off <<= 1) {
      int t = (tid >= off) ? tmp[tid - off] : 0;
      __syncthreads();
      tmp[tid] += t;
      __syncthreads();
    }
    int incl = tmp[tid];
    int c0 = carry;
    if (i < NN) {
      offs[i] = c0 + incl - v;
      cursor[i] = c0 + incl - v;
    }
    __syncthreads();
    if (tid == 255) carry = c0 + incl;
    __syncthreads();
  }
  if (tid == 0) offs[NN] = carry;
}

__global__ __launch_bounds__(256) void fill_kernel(const int* __restrict__ ei,
                                                   int* __restrict__ cursor,
                                                   int* __restrict__ eids) {
  int e = blockIdx.x * 256 + threadIdx.x;
  if (e < NE) {
    int pos = atomicAdd(&cursor[ei[e]], 1);
    eids[pos] = e;
  }
}

// One wave per src node: online softmax over its edges + weighted v accumulation.
__global__ __launch_bounds__(256) void node_kernel(const int* __restrict__ offs,
                                                   const int* __restrict__ eids,
                                                   const float* __restrict__ scores,
                                                   const unsigned short* __restrict__ vws,
                                                   float* __restrict__ out) {
  int tid = threadIdx.x;
  int n = blockIdx.x * 4 + (tid >> 6);
  int lane = tid & 63, h = lane >> 3;
  int o0 = offs[n], deg = offs[n + 1] - o0;
  float m = -INFINITY, s = 0.f;
  float a0 = 0.f, a1 = 0.f, a2 = 0.f, a3 = 0.f;
  for (int i = 0; i < deg; i++) {
    int e = eids[o0 + i];
    float sc = scores[(size_t)e * 8 + h];
    float mn = fmaxf(m, sc);
    float scale = __expf(m - mn);
    float p = __expf(sc - mn);
    s = s * scale + p;
    m = mn;
    u16x4 v = *(const u16x4*)(vws + (size_t)e * DIM + lane * 4);
    a0 = a0 * scale + p * bf2f(v.x);
    a1 = a1 * scale + p * bf2f(v.y);
    a2 = a2 * scale + p * bf2f(v.z);
    a3 = a3 * scale + p * bf2f(v.w);
  }
  float inv = 1.f / (s + 1e-16f);
  f32x4 o;
  o.x = a0 * inv; o.y = a1 * inv; o.z = a2 * inv; o.w = a3 * inv;
  *(f32x4*)(out + (size_t)n * DIM + lane * 4) = o;
}

extern "C" void kernel_launch(void* const* d_in, const int* in_sizes, int n_in,
                              void* d_out, int out_size, void* d_ws, size_t ws_size,
                              hipStream_t stream) {
  const float* x = (const float*)d_in[0];
  const int* ei = (const int*)d_in[1];
  const float* ea = (const float*)d_in[2];
  const float* Wq = (const float*)d_in[3];
  const float* Wk = (const float*)d_in[4];
  const float* Wv = (const float*)d_in[5];
  const float* We = (const float*)d_in[6];
  const float* be = (const float*)d_in[7];

  float* out = (float*)d_out;                       // [NN, 256]
  float* edge_out = out + (size_t)NN * DIM;         // [NE, 256]
  float* q = out;                                   // q scratch (overwritten by node_kernel)
  char* ws = (char*)d_ws;
  unsigned short* wfq = (unsigned short*)(ws + 0);
  unsigned short* wfk = (unsigned short*)(ws + 131072);
  unsigned short* wfv = (unsigned short*)(ws + 262144);
  unsigned short* wfe = (unsigned short*)(ws + 393216);
  unsigned short* vws = (unsigned short*)(ws + 524288);            // [NE,256] bf16
  float* scores = (float*)(ws + 524288 + 163840000);               // [NE,8] f32
  int* counts = (int*)(ws + 524288 + 163840000 + 10240000);
  int* offs = (int*)(ws + 524288 + 163840000 + 10240000 + 80000);
  int* cursor = (int*)(ws + 524288 + 163840000 + 10240000 + 160016);
  int* eids = (int*)(ws + 524288 + 163840000 + 10240000 + 240016);

  hipMemsetAsync(counts, 0, NN * sizeof(int), stream);

  pack_w<<<32, 256, 0, stream>>>(Wq, wfq);
  pack_w<<<32, 256, 0, stream>>>(Wk, wfk);
  pack_w<<<32, 256, 0, stream>>>(Wv, wfv);
  pack_w<<<32, 256, 0, stream>>>(We, wfe);

  q_kernel<<<(NN + 63) / 64, 256, 0, stream>>>(x, wfq, q);
  edge_kernel<<<NE / 128, 512, 0, stream>>>(x, ei, ea, wfk, wfv, wfe, be, q,
                                            vws, scores, edge_out);

  count_kernel<<<(NE + 255) / 256, 256, 0, stream>>>(ei, counts);
  scan_kernel<<<1, 256, 0, stream>>>(counts, offs, cursor);
  fill_kernel<<<(NE + 255) / 256, 256, 0, stream>>>(ei, cursor, eids);

  node_kernel<<<NN / 4, 256, 0, stream>>>(offs, eids, scores, vws, out);
}